// Round 9
// baseline (2931.354 us; speedup 1.0000x reference)
//
#include <hip/hip_runtime.h>
#include <cstdint>
#include <cstddef>

#define DEV __device__ __forceinline__
typedef unsigned short u16;
typedef unsigned int u32;
typedef short bf16x8 __attribute__((ext_vector_type(8)));
typedef float f32x4 __attribute__((ext_vector_type(4)));

typedef __attribute__((address_space(1))) u32 GU32;
typedef __attribute__((address_space(3))) u32 LU32;

DEV float bf2f(u16 v){ u32 x = ((u32)v)<<16; float f; __builtin_memcpy(&f,&x,4); return f; }
DEV u16 f2bf(float f){ u32 x; __builtin_memcpy(&x,&f,4); return (u16)((x + 0x7fffu + ((x>>16)&1u)) >> 16); }

// window-order row r -> hidden_states row (b*4096 + y*64 + x)
DEV int map_row(int r){
  int b = r>>12, rr = r&4095;
  int win = rr>>2, t = rr&3;
  int wy = win>>5, wx = win&31;
  int y = (wy<<1) + (t>>1), x = (wx<<1) + (t&1);
  return (b<<12) + (y<<6) + x;
}

DEV void gl_lds16(const void* g, void* l){
  __builtin_amdgcn_global_load_lds((const GU32*)g, (LU32*)l, 16, 0, 0);
}

DEV void block_red2(float& s, float& ss, float* red){
  #pragma unroll
  for (int o=32;o;o>>=1){ s += __shfl_down(s,o); ss += __shfl_down(ss,o); }
  const int wv = threadIdx.x>>6;
  if ((threadIdx.x&63)==0){ red[wv*2]=s; red[wv*2+1]=ss; }
  __syncthreads();
  s  = red[0]+red[2]+red[4]+red[6];
  ss = red[1]+red[3]+red[5]+red[7];
}

// ---------------- transpose + fp32->bf16 convert: W[K][N] -> WT[N][K] ----------------
__launch_bounds__(256)
__global__ void tconv_k(const float* __restrict__ W, u16* __restrict__ WT, int K, int N){
  __shared__ float tl[64][65];
  const int n0 = blockIdx.x << 6, k0 = blockIdx.y << 6;
  const int tx = threadIdx.x & 63, ty = threadIdx.x >> 6;
  #pragma unroll
  for (int rr = 0; rr < 64; rr += 4)
    tl[rr+ty][tx] = W[(size_t)(k0+rr+ty)*N + (n0+tx)];
  __syncthreads();
  #pragma unroll
  for (int rr = 0; rr < 64; rr += 4)
    WT[(size_t)(n0+rr+ty)*K + (k0+tx)] = f2bf(tl[tx][rr+ty]);
}

// ---------------- LN1: hidden (gathered to window order) -> bf16 ----------------
__launch_bounds__(256)
__global__ void ln1_k(const float* __restrict__ X, const float* __restrict__ g,
                      const float* __restrict__ b, u16* __restrict__ Y){
  __shared__ float red[8];
  const int r = blockIdx.x;
  const float* xr = X + (size_t)map_row(r)*1152;
  const int tid = threadIdx.x;
  const bool has2 = tid < 32;
  float4 v0 = ((const float4*)xr)[tid];
  float4 v1 = {0,0,0,0};
  float s  = v0.x+v0.y+v0.z+v0.w;
  float ss = v0.x*v0.x+v0.y*v0.y+v0.z*v0.z+v0.w*v0.w;
  if (has2){
    v1 = ((const float4*)xr)[tid+256];
    s  += v1.x+v1.y+v1.z+v1.w;
    ss += v1.x*v1.x+v1.y*v1.y+v1.z*v1.z+v1.w*v1.w;
  }
  block_red2(s, ss, red);
  const float mean = s*(1.0f/1152.0f);
  const float rstd = rsqrtf(ss*(1.0f/1152.0f) - mean*mean + 1e-6f);
  u16* yr = Y + (size_t)r*1152;
  {
    float4 gg = ((const float4*)g)[tid];
    float4 bb = ((const float4*)b)[tid];
    ushort4 o;
    o.x = f2bf((v0.x-mean)*rstd*gg.x + bb.x);
    o.y = f2bf((v0.y-mean)*rstd*gg.y + bb.y);
    o.z = f2bf((v0.z-mean)*rstd*gg.z + bb.z);
    o.w = f2bf((v0.w-mean)*rstd*gg.w + bb.w);
    *(ushort4*)(yr + tid*4) = o;
  }
  if (has2){
    float4 gg = ((const float4*)g)[tid+256];
    float4 bb = ((const float4*)b)[tid+256];
    ushort4 o;
    o.x = f2bf((v1.x-mean)*rstd*gg.x + bb.x);
    o.y = f2bf((v1.y-mean)*rstd*gg.y + bb.y);
    o.z = f2bf((v1.z-mean)*rstd*gg.z + bb.z);
    o.w = f2bf((v1.w-mean)*rstd*gg.w + bb.w);
    *(ushort4*)(yr + (tid+256)*4) = o;
  }
}

// ======== 256x256 8-wave 4-phase GEMM (round-8 structure, proven) ========
#define BAR()  asm volatile("s_barrier" ::: "memory")
#define LGKM0() do{ asm volatile("s_waitcnt lgkmcnt(0)" ::: "memory"); \
                    __builtin_amdgcn_sched_barrier(0); }while(0)
#define VMW8() asm volatile("s_waitcnt vmcnt(8)" ::: "memory")
#define VMW6() asm volatile("s_waitcnt vmcnt(6)" ::: "memory")
#define VMW4() asm volatile("s_waitcnt vmcnt(4)" ::: "memory")
#define VMW0() asm volatile("s_waitcnt vmcnt(0)" ::: "memory")
#define WNONE() do{}while(0)

template<int EPI>
__launch_bounds__(512, 1)
__global__ void gemm8p_k(const u16* __restrict__ A, const u16* __restrict__ BT,
                         int M, int N, int K, int lda, int ldb,
                         void* __restrict__ C, int ldc,
                         const float* __restrict__ bias,
                         const float* __restrict__ aux,
                         int nTM, int nTN)
{
  __shared__ __align__(16) u16 LS[2][2][2][8192];   // [dbuf][op][khalf] = 128 KiB
  const int tid = threadIdx.x;
  const int lane = tid & 63;
  const int wave = tid >> 6;
  const int wr = wave >> 2, wc = wave & 3;

  const int bid  = blockIdx.x;
  const int band = 16 * nTN;
  const int bb   = bid / band, rr_ = bid % band;
  int mcnt = nTM - (bb<<4); if (mcnt > 16) mcnt = 16;
  const int mt = (bb<<4) + rr_ % mcnt;
  const int nt = rr_ / mcnt;
  const int m0 = mt << 8, n0 = nt << 8;

  const int lr1 = tid >> 3, sl = tid & 7;
  const int x_  = sl ^ (lr1 & 7);
  const int grow = ((x_ >> 2) << 7) + lr1;
  const int q_   = x_ & 3;
  const u16* aS = A  + (size_t)(m0 + grow)*lda + q_*8;
  const u16* bS = BT + (size_t)(n0 + grow)*ldb + q_*8;
  const size_t aR64 = (size_t)64*lda, bR64 = (size_t)64*ldb;

  const int l15 = lane & 15, l7 = lane & 7, qh = lane >> 4;
  const int aOff = l15*64 + ((((wr<<2)|qh) ^ l7) << 3);
  const int bOff = ((wc&1)<<12) + l15*64 + (((((wc>>1)<<2)|qh) ^ l7) << 3);

  f32x4 acc[8][4] = {};
  bf16x8 af[4], bv[4];
  const int NT = K >> 6;

#define ST(op_, db_, kh_, t_) do{ \
    const u16* src__ = (op_ ? bS : aS) + (size_t)(t_)*64 + (kh_)*32; \
    u16* dst__ = &LS[(db_)][(op_)][(kh_)][tid*8]; \
    gl_lds16(src__, dst__); \
    gl_lds16(src__ + (op_ ? bR64 : aR64), dst__ + 4096); \
  }while(0)

#define READA(base_, mh_) do{ \
    const u16* ap__ = (base_) + aOff + ((mh_)?4096:0); \
    _Pragma("unroll") for (int i__=0;i__<4;i__++) af[i__] = *(const bf16x8*)(ap__ + i__*1024); \
  }while(0)

#define READB(base_) do{ \
    const u16* bp__ = (base_) + bOff; \
    _Pragma("unroll") for (int i__=0;i__<4;i__++) bv[i__] = *(const bf16x8*)(bp__ + i__*1024); \
  }while(0)

#define MFMA16(B_) do{ \
    __builtin_amdgcn_s_setprio(1); \
    _Pragma("unroll") for (int i__=0;i__<4;i__++) \
      _Pragma("unroll") for (int n__=0;n__<4;n__++) \
        acc[(B_)+i__][n__] = __builtin_amdgcn_mfma_f32_16x16x32_bf16(af[i__], bv[n__], acc[(B_)+i__][n__], 0,0,0); \
    __builtin_amdgcn_s_setprio(0); \
  }while(0)

#define GROUP(t_, SE12, SE3, Wp1, Wp3) do{ \
    const int cb__ = (t_) & 1; \
    const u16* rA0__ = &LS[cb__][0][0][0]; \
    const u16* rB0__ = &LS[cb__][1][0][0]; \
    const u16* rA1__ = &LS[cb__][0][1][0]; \
    const u16* rB1__ = &LS[cb__][1][1][0]; \
    READB(rB0__); READA(rA0__, 0); \
    BAR(); LGKM0(); MFMA16(0); \
    READA(rA0__, 1); if (SE12) ST(0, cb__^1, 1, (t_)+1); \
    Wp1(); BAR(); LGKM0(); MFMA16(4); \
    READB(rB1__); READA(rA1__, 0); if (SE12) ST(1, cb__^1, 1, (t_)+1); \
    BAR(); LGKM0(); MFMA16(0); \
    READA(rA1__, 1); if (SE3) { ST(0, cb__, 0, (t_)+2); ST(1, cb__, 0, (t_)+2); } \
    Wp3(); BAR(); LGKM0(); MFMA16(4); \
  }while(0)

  ST(0,0,0,0); ST(1,0,0,0); ST(0,0,1,0); ST(1,0,1,0); ST(0,1,0,1); ST(1,1,0,1);
  VMW8(); BAR();

  int t = 0;
  for (; t < NT-2; ++t) GROUP(t, 1, 1, VMW6, VMW8);
  GROUP(t, 1, 0, VMW6, VMW4); ++t;
  GROUP(t, 0, 0, VMW0, WNONE);

#undef GROUP
#undef MFMA16
#undef READB
#undef READA
#undef ST

  #pragma unroll
  for (int mi=0;mi<8;mi++){
    const int row = m0 + (wr<<7) + (mi<<4) + ((lane>>4)<<2);
    #pragma unroll
    for (int ni=0;ni<4;ni++){
      const int col = n0 + (wc<<6) + (ni<<4) + (lane&15);
      if (col < N){
        const float bvv = bias[col];
        #pragma unroll
        for (int r2=0;r2<4;r2++){
          const int rw = row + r2;
          float v = acc[mi][ni][r2] + bvv;
          if (EPI==0){
            ((u16*)C)[(size_t)rw*ldc + col] = f2bf(v);
          } else if (EPI==1){
            v += aux[(size_t)map_row(rw)*ldc + col];
            ((u16*)C)[(size_t)rw*ldc + col] = f2bf(v);
          } else if (EPI==2){
            const float x = v;
            const float c = 0.7978845608028654f*(x + 0.044715f*x*x*x);
            v = 0.5f*x*(1.0f + tanhf(c));
            ((u16*)C)[(size_t)rw*ldc + col] = f2bf(v);
          } else {
            v += aux[(size_t)rw*ldc + col];
            ((float*)C)[(size_t)rw*ldc + col] = v;
          }
        }
      }
    }
  }
}

// ---------------- 128x128 GEMM (round-1 proven; high occupancy, for small-N GEMMs) ----------------
template<int EPI>
__launch_bounds__(256,2)
__global__ void gemm_k(const u16* __restrict__ A, const u16* __restrict__ BT,
                       int M, int N, int K, int lda,
                       void* __restrict__ C, int ldc,
                       const float* __restrict__ bias,
                       const float* __restrict__ aux,
                       int row_off)
{
  __shared__ __align__(16) u16 As[128*64];
  __shared__ __align__(16) u16 Bs[128*64];
  const int tid = threadIdx.x;
  const int lane = tid & 63;
  const int wave = tid >> 6;
  const int wr = wave >> 1, wc = wave & 1;
  const int m0 = blockIdx.y << 7, n0 = blockIdx.x << 7;

  f32x4 acc[4][4] = {};

  const int srow = tid >> 3;
  const int scol = (tid & 7) << 3;
  const u16* Ab = A  + (size_t)(m0 + srow)*lda + scol;
  const u16* Bb = BT + (size_t)(n0 + srow)*K   + scol;

  for (int kt = 0; kt < K; kt += 64) {
    #pragma unroll
    for (int i=0;i<4;i++)
      gl_lds16(Ab + kt + (size_t)(i*32)*lda, &As[(size_t)(i*256+tid)*8]);
    #pragma unroll
    for (int i=0;i<4;i++)
      gl_lds16(Bb + kt + (size_t)(i*32)*K, &Bs[(size_t)(i*256+tid)*8]);
    __syncthreads();
    #pragma unroll
    for (int kk=0; kk<64; kk+=32) {
      bf16x8 af[4], bv[4];
      const int ko = kk + ((lane>>4)<<3);
      #pragma unroll
      for (int mi=0;mi<4;mi++)
        af[mi] = *(const bf16x8*)&As[(((wr<<6)+(mi<<4)+(lane&15))<<6) + ko];
      #pragma unroll
      for (int ni=0;ni<4;ni++)
        bv[ni] = *(const bf16x8*)&Bs[(((wc<<6)+(ni<<4)+(lane&15))<<6) + ko];
      #pragma unroll
      for (int mi=0;mi<4;mi++)
        #pragma unroll
        for (int ni=0;ni<4;ni++)
          acc[mi][ni] = __builtin_amdgcn_mfma_f32_16x16x32_bf16(af[mi], bv[ni], acc[mi][ni], 0,0,0);
    }
    __syncthreads();
  }

  #pragma unroll
  for (int mi=0;mi<4;mi++){
    const int rbase = m0 + (wr<<6) + (mi<<4) + ((lane>>4)<<2);
    #pragma unroll
    for (int ni=0;ni<4;ni++){
      const int col = n0 + (wc<<6) + (ni<<4) + (lane&15);
      if (col < N) {
        const float bvv = bias[col];
        #pragma unroll
        for (int r2=0;r2<4;r2++){
          const int row = rbase + r2;
          float v = acc[mi][ni][r2] + bvv;
          if (EPI==0){
            ((u16*)C)[(size_t)row*ldc + col] = f2bf(v);
          } else if (EPI==1){
            const int src = map_row(row + row_off);
            v += aux[(size_t)src*ldc + col];
            ((u16*)C)[(size_t)row*ldc + col] = f2bf(v);
          } else if (EPI==2){
            const float x = v;
            const float c = 0.7978845608028654f*(x + 0.044715f*x*x*x);
            v = 0.5f*x*(1.0f + tanhf(c));
            ((u16*)C)[(size_t)row*ldc + col] = f2bf(v);
          } else {
            v += aux[(size_t)row*ldc + col];
            ((float*)C)[(size_t)row*ldc + col] = v;
          }
        }
      }
    }
  }
}

// ---------------- window attention: 4 tokens x 16 heads, head_dim 72 ----------------
__launch_bounds__(256)
__global__ void attn_k(const u16* __restrict__ QKV, u16* __restrict__ O){
  const int wave = threadIdx.x >> 6, lane = threadIdx.x & 63;
  const int wg = blockIdx.x*4 + wave;
  const int t = lane >> 4, h = lane & 15;
  const u16* base = QKV + (size_t)wg*4*3456;

  float q[72];
  {
    const u16* qp = base + t*3456 + h*72;
    #pragma unroll
    for (int i=0;i<9;i++){
      bf16x8 v = *(const bf16x8*)(qp + i*8);
      #pragma unroll
      for (int j=0;j<8;j++) q[i*8+j] = bf2f((u16)v[j]);
    }
  }
  float sc[4];
  #pragma unroll
  for (int tp=0;tp<4;tp++){
    const u16* kp = base + tp*3456 + 1152 + h*72;
    float a = 0.f;
    #pragma unroll
    for (int i=0;i<9;i++){
      bf16x8 v = *(const bf16x8*)(kp + i*8);
      #pragma unroll
      for (int j=0;j<8;j++) a += q[i*8+j]*bf2f((u16)v[j]);
    }
    sc[tp] = a * 0.11785113019775793f;
  }
  const float mx = fmaxf(fmaxf(sc[0],sc[1]), fmaxf(sc[2],sc[3]));
  float p[4]; float sum = 0.f;
  #pragma unroll
  for (int tp=0;tp<4;tp++){ p[tp] = __expf(sc[tp]-mx); sum += p[tp]; }
  const float inv = 1.0f/sum;
  float o[72];
  #pragma unroll
  for (int i=0;i<72;i++) o[i] = 0.f;
  #pragma unroll
  for (int tp=0;tp<4;tp++){
    const float w = p[tp]*inv;
    const u16* vp = base + tp*3456 + 2304 + h*72;
    #pragma unroll
    for (int i=0;i<9;i++){
      bf16x8 v = *(const bf16x8*)(vp + i*8);
      #pragma unroll
      for (int j=0;j<8;j++) o[i*8+j] += w*bf2f((u16)v[j]);
    }
  }
  u16* op = O + (size_t)(wg*4+t)*1152 + h*72;
  #pragma unroll
  for (int i=0;i<9;i++){
    bf16x8 sv;
    #pragma unroll
    for (int j=0;j<8;j++) sv[j] = (short)f2bf(o[i*8+j]);
    *(bf16x8*)(op + i*8) = sv;
  }
}

// ---------------- fused 2x2 merge: res mean + LN(4608) -> xfln bf16 ----------------
__launch_bounds__(256)
__global__ void ln2res_k(const u16* __restrict__ hs2, const float* __restrict__ g,
                         const float* __restrict__ b, u16* __restrict__ Y,
                         float* __restrict__ res){
  __shared__ float buf[4608];
  __shared__ float red[8];
  const int w = blockIdx.x;
  const u16* xr = hs2 + (size_t)w*4608;
  float s = 0.f, ss = 0.f;
  for (int i = threadIdx.x*8; i < 4608; i += 2048){
    bf16x8 v = *(const bf16x8*)(xr + i);
    #pragma unroll
    for (int j=0;j<8;j++){
      float f = bf2f((u16)v[j]);
      buf[i+j] = f; s += f; ss += f*f;
    }
  }
  block_red2(s, ss, red);
  const float mean = s*(1.0f/4608.0f);
  const float rstd = rsqrtf(ss*(1.0f/4608.0f) - mean*mean + 1e-6f);
  u16* yr = Y + (size_t)w*4608;
  for (int i = threadIdx.x*8; i < 4608; i += 2048){
    bf16x8 sv;
    #pragma unroll
    for (int j=0;j<8;j++)
      sv[j] = (short)f2bf((buf[i+j]-mean)*rstd*g[i+j] + b[i+j]);
    *(bf16x8*)(yr + i) = sv;
  }
  for (int d = threadIdx.x; d < 1152; d += 256)
    res[(size_t)w*1152 + d] = 0.25f*(buf[d]+buf[d+1152]+buf[d+2304]+buf[d+3456]);
}

// ---------------- tail: new_tgt_sizes + attention mask ----------------
__global__ void tail_k(const int* __restrict__ tgt, float* __restrict__ out){
  const int tid = blockIdx.x*blockDim.x + threadIdx.x;
  float* t_out = out + 9437184;
  float* m_out = t_out + 16;
  if (tid < 16) t_out[tid] = (float)(tgt[tid] / 2);
  for (int i = tid; i < 8192; i += 256*32){
    const int b = i >> 10, w = i & 1023;
    const int lim = (tgt[b*2]/2) * (tgt[b*2+1]/2);
    m_out[i] = (w < lim) ? 0.0f : -3.40282346638528859812e+38f;
  }
}

extern "C" void kernel_launch(void* const* d_in, const int* in_sizes, int n_in,
                              void* d_out, int out_size, void* d_ws, size_t ws_size,
                              hipStream_t stream){
  const float* hidden = (const float*)d_in[0];
  const int*   tgt    = (const int*)  d_in[1];
  const float* ln1_g  = (const float*)d_in[3];
  const float* ln1_b  = (const float*)d_in[4];
  const float* qkv_w  = (const float*)d_in[5];
  const float* qkv_b  = (const float*)d_in[6];
  const float* out_w  = (const float*)d_in[7];
  const float* out_b  = (const float*)d_in[8];
  const float* pre_g  = (const float*)d_in[9];
  const float* pre_b  = (const float*)d_in[10];
  const float* w1     = (const float*)d_in[11];
  const float* b1     = (const float*)d_in[12];
  const float* w2     = (const float*)d_in[13];
  const float* b2     = (const float*)d_in[14];
  float* out = (float*)d_out;

  char* p = (char*)d_ws;
  auto alloc = [&](size_t bytes)->void*{ void* r = p; p += (bytes + 255) & ~(size_t)255; return r; };
  u16* w1T = (u16*)alloc(17216ull*4608*2);   // keep FIRST (N-tail B-row overreads land in w2T)
  u16* w2T = (u16*)alloc(1152ull*17216*2);   // overread -> wqT
  u16* wqT = (u16*)alloc(3456ull*1152*2);    // overread -> woT
  u16* woT = (u16*)alloc(1152ull*1152*2);    // overread -> Xln
  u16* Xln = (u16*)alloc(32768ull*1152*2);   // LN1 out; later attn O; later h1 (with hs2)
  char* qr = (char*)alloc(32768ull*3456*2);  // QKV | later hs2 @0, res @75.5M, xfln @151M
  u16*   QKV  = (u16*)qr;
  u16*   hs2  = (u16*)qr;
  float* res  = (float*)(qr + 75497472);
  u16*   xfln = (u16*)(qr + 150994944);
  u16*   h1   = Xln;                         // [4096][17216] bf16 = 141 MB fits in Xln+hs2

  // 1) weight transpose+convert
  tconv_k<<<dim3(17216/64, 4608/64), 256, 0, stream>>>(w1, w1T, 4608, 17216);
  tconv_k<<<dim3(1152/64, 17216/64), 256, 0, stream>>>(w2, w2T, 17216, 1152);
  tconv_k<<<dim3(3456/64, 1152/64), 256, 0, stream>>>(qkv_w, wqT, 1152, 3456);
  tconv_k<<<dim3(1152/64, 1152/64), 256, 0, stream>>>(out_w, woT, 1152, 1152);
  // 2) LN1 (window-order gather)
  ln1_k<<<32768, 256, 0, stream>>>(hidden, ln1_g, ln1_b, Xln);
  // 3) QKV GEMM: M=32768, N=3456 (14 tiles, tail guarded), K=1152
  gemm8p_k<0><<<dim3(128*14), 512, 0, stream>>>(Xln, wqT, 32768, 3456, 1152, 1152, 1152,
                                                QKV, 3456, qkv_b, nullptr, 128, 14);
  // 4) window attention -> O (reuses Xln)
  attn_k<<<2048, 256, 0, stream>>>(QKV, Xln);
  // 5) out-proj + residual gather -> hs2: N=1152 (5 tiles), K=1152
  gemm8p_k<1><<<dim3(128*5), 512, 0, stream>>>(Xln, woT, 32768, 1152, 1152, 1152, 1152,
                                               hs2, 1152, out_b, hidden, 128, 5);
  // 6) merge: res mean + LN(4608) -> xfln (+res); hs2 dead afterwards
  ln2res_k<<<8192, 256, 0, stream>>>(hs2, pre_g, pre_b, xfln, res);
  // 7) MLP, M-chunked through h1 (CR=4096: 2 chunks).
  //    MLP1 (N=17216) on 256^2 kernel (1088 blocks); MLP2 (N=1152) on 128^2 kernel
  //    (288 blocks, ~3 blocks/CU) — the 256^2 grid was only 85 blocks = 33% of CUs.
  for (int r0 = 0; r0 < 8192; r0 += 4096){
    const int m = 4096;
    gemm8p_k<2><<<dim3((m>>8)*68), 512, 0, stream>>>(xfln + (size_t)r0*4608, w1T,
                                                     m, 17216, 4608, 4608, 4608,
                                                     h1, 17216, b1, nullptr, m>>8, 68);
    gemm_k<3><<<dim3(9, m>>7), 256, 0, stream>>>(h1, w2T,
                                                 m, 1152, 17216, 17216,
                                                 out + (size_t)r0*1152, 1152, b2,
                                                 res + (size_t)r0*1152, 0);
  }
  // 8) tail outputs
  tail_k<<<32, 256, 0, stream>>>(tgt, out);
}

// Round 10
// 2410.638 us; speedup vs baseline: 1.2160x; 1.2160x over previous
//
#include <hip/hip_runtime.h>
#include <cstdint>
#include <cstddef>

#define DEV __device__ __forceinline__
typedef unsigned short u16;
typedef unsigned int u32;
typedef short bf16x8 __attribute__((ext_vector_type(8)));
typedef float f32x4 __attribute__((ext_vector_type(4)));

typedef __attribute__((address_space(1))) u32 GU32;
typedef __attribute__((address_space(3))) u32 LU32;

DEV float bf2f(u16 v){ u32 x = ((u32)v)<<16; float f; __builtin_memcpy(&f,&x,4); return f; }
DEV u16 f2bf(float f){ u32 x; __builtin_memcpy(&x,&f,4); return (u16)((x + 0x7fffu + ((x>>16)&1u)) >> 16); }

// window-order row r -> hidden_states row (b*4096 + y*64 + x)
DEV int map_row(int r){
  int b = r>>12, rr = r&4095;
  int win = rr>>2, t = rr&3;
  int wy = win>>5, wx = win&31;
  int y = (wy<<1) + (t>>1), x = (wx<<1) + (t&1);
  return (b<<12) + (y<<6) + x;
}

DEV void gl_lds16(const void* g, void* l){
  __builtin_amdgcn_global_load_lds((const GU32*)g, (LU32*)l, 16, 0, 0);
}

DEV void block_red2(float& s, float& ss, float* red){
  #pragma unroll
  for (int o=32;o;o>>=1){ s += __shfl_down(s,o); ss += __shfl_down(ss,o); }
  const int wv = threadIdx.x>>6;
  if ((threadIdx.x&63)==0){ red[wv*2]=s; red[wv*2+1]=ss; }
  __syncthreads();
  s  = red[0]+red[2]+red[4]+red[6];
  ss = red[1]+red[3]+red[5]+red[7];
}

// ---------------- transpose + fp32->bf16 convert: W[K][N] -> WT[N][K] ----------------
__launch_bounds__(256)
__global__ void tconv_k(const float* __restrict__ W, u16* __restrict__ WT, int K, int N){
  __shared__ float tl[64][65];
  const int n0 = blockIdx.x << 6, k0 = blockIdx.y << 6;
  const int tx = threadIdx.x & 63, ty = threadIdx.x >> 6;
  #pragma unroll
  for (int rr = 0; rr < 64; rr += 4)
    tl[rr+ty][tx] = W[(size_t)(k0+rr+ty)*N + (n0+tx)];
  __syncthreads();
  #pragma unroll
  for (int rr = 0; rr < 64; rr += 4)
    WT[(size_t)(n0+rr+ty)*K + (k0+tx)] = f2bf(tl[tx][rr+ty]);
}

// ---------------- LN1: hidden (gathered to window order) -> bf16 ----------------
__launch_bounds__(256)
__global__ void ln1_k(const float* __restrict__ X, const float* __restrict__ g,
                      const float* __restrict__ b, u16* __restrict__ Y){
  __shared__ float red[8];
  const int r = blockIdx.x;
  const float* xr = X + (size_t)map_row(r)*1152;
  const int tid = threadIdx.x;
  const bool has2 = tid < 32;
  float4 v0 = ((const float4*)xr)[tid];
  float4 v1 = {0,0,0,0};
  float s  = v0.x+v0.y+v0.z+v0.w;
  float ss = v0.x*v0.x+v0.y*v0.y+v0.z*v0.z+v0.w*v0.w;
  if (has2){
    v1 = ((const float4*)xr)[tid+256];
    s  += v1.x+v1.y+v1.z+v1.w;
    ss += v1.x*v1.x+v1.y*v1.y+v1.z*v1.z+v1.w*v1.w;
  }
  block_red2(s, ss, red);
  const float mean = s*(1.0f/1152.0f);
  const float rstd = rsqrtf(ss*(1.0f/1152.0f) - mean*mean + 1e-6f);
  u16* yr = Y + (size_t)r*1152;
  {
    float4 gg = ((const float4*)g)[tid];
    float4 bb = ((const float4*)b)[tid];
    ushort4 o;
    o.x = f2bf((v0.x-mean)*rstd*gg.x + bb.x);
    o.y = f2bf((v0.y-mean)*rstd*gg.y + bb.y);
    o.z = f2bf((v0.z-mean)*rstd*gg.z + bb.z);
    o.w = f2bf((v0.w-mean)*rstd*gg.w + bb.w);
    *(ushort4*)(yr + tid*4) = o;
  }
  if (has2){
    float4 gg = ((const float4*)g)[tid+256];
    float4 bb = ((const float4*)b)[tid+256];
    ushort4 o;
    o.x = f2bf((v1.x-mean)*rstd*gg.x + bb.x);
    o.y = f2bf((v1.y-mean)*rstd*gg.y + bb.y);
    o.z = f2bf((v1.z-mean)*rstd*gg.z + bb.z);
    o.w = f2bf((v1.w-mean)*rstd*gg.w + bb.w);
    *(ushort4*)(yr + (tid+256)*4) = o;
  }
}

// ======== 256x256 8-wave 4-phase GEMM (round-8 structure, proven) ========
#define BAR()  asm volatile("s_barrier" ::: "memory")
#define LGKM0() do{ asm volatile("s_waitcnt lgkmcnt(0)" ::: "memory"); \
                    __builtin_amdgcn_sched_barrier(0); }while(0)
#define VMW8() asm volatile("s_waitcnt vmcnt(8)" ::: "memory")
#define VMW6() asm volatile("s_waitcnt vmcnt(6)" ::: "memory")
#define VMW4() asm volatile("s_waitcnt vmcnt(4)" ::: "memory")
#define VMW0() asm volatile("s_waitcnt vmcnt(0)" ::: "memory")
#define WNONE() do{}while(0)

template<int EPI>
__launch_bounds__(512, 1)
__global__ void gemm8p_k(const u16* __restrict__ A, const u16* __restrict__ BT,
                         int M, int N, int K, int lda, int ldb,
                         void* __restrict__ C, int ldc,
                         const float* __restrict__ bias,
                         const float* __restrict__ aux,
                         int nTM, int nTN)
{
  __shared__ __align__(16) u16 LS[2][2][2][8192];   // [dbuf][op][khalf] = 128 KiB
  const int tid = threadIdx.x;
  const int lane = tid & 63;
  const int wave = tid >> 6;
  const int wr = wave >> 2, wc = wave & 3;

  const int bid  = blockIdx.x;
  const int band = 16 * nTN;
  const int bb   = bid / band, rr_ = bid % band;
  int mcnt = nTM - (bb<<4); if (mcnt > 16) mcnt = 16;
  const int mt = (bb<<4) + rr_ % mcnt;
  const int nt = rr_ / mcnt;
  const int m0 = mt << 8, n0 = nt << 8;

  const int lr1 = tid >> 3, sl = tid & 7;
  const int x_  = sl ^ (lr1 & 7);
  const int grow = ((x_ >> 2) << 7) + lr1;
  const int q_   = x_ & 3;
  const u16* aS = A  + (size_t)(m0 + grow)*lda + q_*8;
  const u16* bS = BT + (size_t)(n0 + grow)*ldb + q_*8;
  const size_t aR64 = (size_t)64*lda, bR64 = (size_t)64*ldb;

  const int l15 = lane & 15, l7 = lane & 7, qh = lane >> 4;
  const int aOff = l15*64 + ((((wr<<2)|qh) ^ l7) << 3);
  const int bOff = ((wc&1)<<12) + l15*64 + (((((wc>>1)<<2)|qh) ^ l7) << 3);

  f32x4 acc[8][4] = {};
  bf16x8 af[4], bv[4];
  const int NT = K >> 6;

#define ST(op_, db_, kh_, t_) do{ \
    const u16* src__ = (op_ ? bS : aS) + (size_t)(t_)*64 + (kh_)*32; \
    u16* dst__ = &LS[(db_)][(op_)][(kh_)][tid*8]; \
    gl_lds16(src__, dst__); \
    gl_lds16(src__ + (op_ ? bR64 : aR64), dst__ + 4096); \
  }while(0)

#define READA(base_, mh_) do{ \
    const u16* ap__ = (base_) + aOff + ((mh_)?4096:0); \
    _Pragma("unroll") for (int i__=0;i__<4;i__++) af[i__] = *(const bf16x8*)(ap__ + i__*1024); \
  }while(0)

#define READB(base_) do{ \
    const u16* bp__ = (base_) + bOff; \
    _Pragma("unroll") for (int i__=0;i__<4;i__++) bv[i__] = *(const bf16x8*)(bp__ + i__*1024); \
  }while(0)

#define MFMA16(B_) do{ \
    __builtin_amdgcn_s_setprio(1); \
    _Pragma("unroll") for (int i__=0;i__<4;i__++) \
      _Pragma("unroll") for (int n__=0;n__<4;n__++) \
        acc[(B_)+i__][n__] = __builtin_amdgcn_mfma_f32_16x16x32_bf16(af[i__], bv[n__], acc[(B_)+i__][n__], 0,0,0); \
    __builtin_amdgcn_s_setprio(0); \
  }while(0)

#define GROUP(t_, SE12, SE3, Wp1, Wp3) do{ \
    const int cb__ = (t_) & 1; \
    const u16* rA0__ = &LS[cb__][0][0][0]; \
    const u16* rB0__ = &LS[cb__][1][0][0]; \
    const u16* rA1__ = &LS[cb__][0][1][0]; \
    const u16* rB1__ = &LS[cb__][1][1][0]; \
    READB(rB0__); READA(rA0__, 0); \
    BAR(); LGKM0(); MFMA16(0); \
    READA(rA0__, 1); if (SE12) ST(0, cb__^1, 1, (t_)+1); \
    Wp1(); BAR(); LGKM0(); MFMA16(4); \
    READB(rB1__); READA(rA1__, 0); if (SE12) ST(1, cb__^1, 1, (t_)+1); \
    BAR(); LGKM0(); MFMA16(0); \
    READA(rA1__, 1); if (SE3) { ST(0, cb__, 0, (t_)+2); ST(1, cb__, 0, (t_)+2); } \
    Wp3(); BAR(); LGKM0(); MFMA16(4); \
  }while(0)

  ST(0,0,0,0); ST(1,0,0,0); ST(0,0,1,0); ST(1,0,1,0); ST(0,1,0,1); ST(1,1,0,1);
  VMW8(); BAR();

  int t = 0;
  for (; t < NT-2; ++t) GROUP(t, 1, 1, VMW6, VMW8);
  GROUP(t, 1, 0, VMW6, VMW4); ++t;
  GROUP(t, 0, 0, VMW0, WNONE);

#undef GROUP
#undef MFMA16
#undef READB
#undef READA
#undef ST

  #pragma unroll
  for (int mi=0;mi<8;mi++){
    const int row = m0 + (wr<<7) + (mi<<4) + ((lane>>4)<<2);
    #pragma unroll
    for (int ni=0;ni<4;ni++){
      const int col = n0 + (wc<<6) + (ni<<4) + (lane&15);
      if (col < N){
        const float bvv = bias[col];
        #pragma unroll
        for (int r2=0;r2<4;r2++){
          const int rw = row + r2;
          float v = acc[mi][ni][r2] + bvv;
          if (EPI==0){
            ((u16*)C)[(size_t)rw*ldc + col] = f2bf(v);
          } else if (EPI==1){
            v += aux[(size_t)map_row(rw)*ldc + col];
            ((u16*)C)[(size_t)rw*ldc + col] = f2bf(v);
          } else if (EPI==2){
            const float x = v;
            const float c = 0.7978845608028654f*(x + 0.044715f*x*x*x);
            v = 0.5f*x*(1.0f + tanhf(c));
            ((u16*)C)[(size_t)rw*ldc + col] = f2bf(v);
          } else {
            v += aux[(size_t)rw*ldc + col];
            ((float*)C)[(size_t)rw*ldc + col] = v;
          }
        }
      }
    }
  }
}

// ---------------- window attention: 4 tokens x 16 heads, head_dim 72 ----------------
__launch_bounds__(256)
__global__ void attn_k(const u16* __restrict__ QKV, u16* __restrict__ O){
  const int wave = threadIdx.x >> 6, lane = threadIdx.x & 63;
  const int wg = blockIdx.x*4 + wave;
  const int t = lane >> 4, h = lane & 15;
  const u16* base = QKV + (size_t)wg*4*3456;

  float q[72];
  {
    const u16* qp = base + t*3456 + h*72;
    #pragma unroll
    for (int i=0;i<9;i++){
      bf16x8 v = *(const bf16x8*)(qp + i*8);
      #pragma unroll
      for (int j=0;j<8;j++) q[i*8+j] = bf2f((u16)v[j]);
    }
  }
  float sc[4];
  #pragma unroll
  for (int tp=0;tp<4;tp++){
    const u16* kp = base + tp*3456 + 1152 + h*72;
    float a = 0.f;
    #pragma unroll
    for (int i=0;i<9;i++){
      bf16x8 v = *(const bf16x8*)(kp + i*8);
      #pragma unroll
      for (int j=0;j<8;j++) a += q[i*8+j]*bf2f((u16)v[j]);
    }
    sc[tp] = a * 0.11785113019775793f;
  }
  const float mx = fmaxf(fmaxf(sc[0],sc[1]), fmaxf(sc[2],sc[3]));
  float p[4]; float sum = 0.f;
  #pragma unroll
  for (int tp=0;tp<4;tp++){ p[tp] = __expf(sc[tp]-mx); sum += p[tp]; }
  const float inv = 1.0f/sum;
  float o[72];
  #pragma unroll
  for (int i=0;i<72;i++) o[i] = 0.f;
  #pragma unroll
  for (int tp=0;tp<4;tp++){
    const float w = p[tp]*inv;
    const u16* vp = base + tp*3456 + 2304 + h*72;
    #pragma unroll
    for (int i=0;i<9;i++){
      bf16x8 v = *(const bf16x8*)(vp + i*8);
      #pragma unroll
      for (int j=0;j<8;j++) o[i*8+j] += w*bf2f((u16)v[j]);
    }
  }
  u16* op = O + (size_t)(wg*4+t)*1152 + h*72;
  #pragma unroll
  for (int i=0;i<9;i++){
    bf16x8 sv;
    #pragma unroll
    for (int j=0;j<8;j++) sv[j] = (short)f2bf(o[i*8+j]);
    *(bf16x8*)(op + i*8) = sv;
  }
}

// ---------------- fused 2x2 merge: res mean + LN(4608) -> xfln bf16 ----------------
__launch_bounds__(256)
__global__ void ln2res_k(const u16* __restrict__ hs2, const float* __restrict__ g,
                         const float* __restrict__ b, u16* __restrict__ Y,
                         float* __restrict__ res){
  __shared__ float buf[4608];
  __shared__ float red[8];
  const int w = blockIdx.x;
  const u16* xr = hs2 + (size_t)w*4608;
  float s = 0.f, ss = 0.f;
  for (int i = threadIdx.x*8; i < 4608; i += 2048){
    bf16x8 v = *(const bf16x8*)(xr + i);
    #pragma unroll
    for (int j=0;j<8;j++){
      float f = bf2f((u16)v[j]);
      buf[i+j] = f; s += f; ss += f*f;
    }
  }
  block_red2(s, ss, red);
  const float mean = s*(1.0f/4608.0f);
  const float rstd = rsqrtf(ss*(1.0f/4608.0f) - mean*mean + 1e-6f);
  u16* yr = Y + (size_t)w*4608;
  for (int i = threadIdx.x*8; i < 4608; i += 2048){
    bf16x8 sv;
    #pragma unroll
    for (int j=0;j<8;j++)
      sv[j] = (short)f2bf((buf[i+j]-mean)*rstd*g[i+j] + b[i+j]);
    *(bf16x8*)(yr + i) = sv;
  }
  for (int d = threadIdx.x; d < 1152; d += 256)
    res[(size_t)w*1152 + d] = 0.25f*(buf[d]+buf[d+1152]+buf[d+2304]+buf[d+3456]);
}

// ---------------- tail: new_tgt_sizes + attention mask ----------------
__global__ void tail_k(const int* __restrict__ tgt, float* __restrict__ out){
  const int tid = blockIdx.x*blockDim.x + threadIdx.x;
  float* t_out = out + 9437184;
  float* m_out = t_out + 16;
  if (tid < 16) t_out[tid] = (float)(tgt[tid] / 2);
  for (int i = tid; i < 8192; i += 256*32){
    const int b = i >> 10, w = i & 1023;
    const int lim = (tgt[b*2]/2) * (tgt[b*2+1]/2);
    m_out[i] = (w < lim) ? 0.0f : -3.40282346638528859812e+38f;
  }
}

extern "C" void kernel_launch(void* const* d_in, const int* in_sizes, int n_in,
                              void* d_out, int out_size, void* d_ws, size_t ws_size,
                              hipStream_t stream){
  const float* hidden = (const float*)d_in[0];
  const int*   tgt    = (const int*)  d_in[1];
  const float* ln1_g  = (const float*)d_in[3];
  const float* ln1_b  = (const float*)d_in[4];
  const float* qkv_w  = (const float*)d_in[5];
  const float* qkv_b  = (const float*)d_in[6];
  const float* out_w  = (const float*)d_in[7];
  const float* out_b  = (const float*)d_in[8];
  const float* pre_g  = (const float*)d_in[9];
  const float* pre_b  = (const float*)d_in[10];
  const float* w1     = (const float*)d_in[11];
  const float* b1     = (const float*)d_in[12];
  const float* w2     = (const float*)d_in[13];
  const float* b2     = (const float*)d_in[14];
  float* out = (float*)d_out;

  char* p = (char*)d_ws;
  auto alloc = [&](size_t bytes)->void*{ void* r = p; p += (bytes + 255) & ~(size_t)255; return r; };
  u16* w1T = (u16*)alloc(17216ull*4608*2);   // keep FIRST (N-tail B-row overreads land in w2T)
  u16* w2T = (u16*)alloc(1152ull*17216*2);   // overread -> wqT
  u16* wqT = (u16*)alloc(3456ull*1152*2);    // overread -> woT
  u16* woT = (u16*)alloc(1152ull*1152*2);    // overread -> Xln
  u16* Xln = (u16*)alloc(32768ull*1152*2);   // LN1 out; later attn O
  char* qr = (char*)alloc(32768ull*3456*2);  // QKV | later hs2 @0, res @75.5M, xfln @151M
  u16*   QKV  = (u16*)qr;
  u16*   hs2  = (u16*)qr;
  float* res  = (float*)(qr + 75497472);
  u16*   xfln = (u16*)(qr + 150994944);
  // h1 in the TAIL of the workspace (round-1 scheme): CR=8192 when ws allows ->
  // single MLP1 dispatch (2176 blocks) and single MLP2 dispatch (160 blocks, one
  // launch-wave) instead of 2x85-block MLP2 at 33% CU utilization.
  size_t fixed = (size_t)(p - (char*)d_ws);
  size_t avail = ws_size > fixed ? ws_size - fixed : 0;
  long long crl = (long long)((avail / (17216ull*2)) & ~(size_t)255);
  int CR = (int)(crl > 8192 ? 8192 : crl);
  if (CR < 256) CR = 256;
  u16* h1 = (u16*)p;                         // [CR][17216] bf16

  // 1) weight transpose+convert
  tconv_k<<<dim3(17216/64, 4608/64), 256, 0, stream>>>(w1, w1T, 4608, 17216);
  tconv_k<<<dim3(1152/64, 17216/64), 256, 0, stream>>>(w2, w2T, 17216, 1152);
  tconv_k<<<dim3(3456/64, 1152/64), 256, 0, stream>>>(qkv_w, wqT, 1152, 3456);
  tconv_k<<<dim3(1152/64, 1152/64), 256, 0, stream>>>(out_w, woT, 1152, 1152);
  // 2) LN1 (window-order gather)
  ln1_k<<<32768, 256, 0, stream>>>(hidden, ln1_g, ln1_b, Xln);
  // 3) QKV GEMM: M=32768, N=3456 (14 tiles, tail guarded), K=1152
  gemm8p_k<0><<<dim3(128*14), 512, 0, stream>>>(Xln, wqT, 32768, 3456, 1152, 1152, 1152,
                                                QKV, 3456, qkv_b, nullptr, 128, 14);
  // 4) window attention -> O (reuses Xln)
  attn_k<<<2048, 256, 0, stream>>>(QKV, Xln);
  // 5) out-proj + residual gather -> hs2: N=1152 (5 tiles), K=1152
  gemm8p_k<1><<<dim3(128*5), 512, 0, stream>>>(Xln, woT, 32768, 1152, 1152, 1152, 1152,
                                               hs2, 1152, out_b, hidden, 128, 5);
  // 6) merge: res mean + LN(4608) -> xfln (+res); hs2 dead afterwards
  ln2res_k<<<8192, 256, 0, stream>>>(hs2, pre_g, pre_b, xfln, res);
  // 7) MLP through h1 (single pass when CR=8192)
  for (int r0 = 0; r0 < 8192; r0 += CR){
    const int m = (8192 - r0 < CR) ? (8192 - r0) : CR;
    gemm8p_k<2><<<dim3((m>>8)*68), 512, 0, stream>>>(xfln + (size_t)r0*4608, w1T,
                                                     m, 17216, 4608, 4608, 4608,
                                                     h1, 17216, b1, nullptr, m>>8, 68);
    gemm8p_k<3><<<dim3((m>>8)*5), 512, 0, stream>>>(h1, w2T,
                                                    m, 1152, 17216, 17216, 17216,
                                                    out + (size_t)r0*1152, 1152, b2,
                                                    res + (size_t)r0*1152, m>>8, 5);
  }
  // 8) tail outputs
  tail_k<<<32, 256, 0, stream>>>(tgt, out);
}